// Round 17
// baseline (324.249 us; speedup 1.0000x reference)
//
#include <hip/hip_runtime.h>

#define T_TOK 4096
#define NEXP  8
#define HID   1024
#define INTER 2816
#define CAP   2048

typedef __attribute__((ext_vector_type(8))) short bf16x8;
typedef __attribute__((ext_vector_type(4))) float f32x4;

__device__ __forceinline__ float bf2f(unsigned short u){
  union { unsigned int i; float f; } c; c.i = ((unsigned int)u) << 16; return c.f;
}
__device__ __forceinline__ unsigned short f2bf(float f){
  union { float f; unsigned int i; } c; c.f = f;
  unsigned int x = c.i;
  unsigned int r = (x + 0x7fffu + ((x >> 16) & 1u)) >> 16;
  return (unsigned short)r;
}

__device__ __forceinline__ void gload_lds16(const void* g, void* l){
  __builtin_amdgcn_global_load_lds(
      (const __attribute__((address_space(1))) void*)g,
      (__attribute__((address_space(3))) void*)l, 16, 0, 0);
}

// ---------------- routing: 1 block, 512 threads, wave w owns expert w ----------
__global__ void routing_kernel(const int* __restrict__ eidx,
                               int* __restrict__ assign,
                               int* __restrict__ perm,
                               int* __restrict__ counts)
{
  int tid = threadIdx.x;
  for (int i = tid; i < NEXP * CAP; i += 512) assign[i] = 0;
  __syncthreads();
  int e = tid >> 6;
  int lane = tid & 63;
  int base = 0;
  for (int t0 = 0; t0 < T_TOK; t0 += 64){
    int t = t0 + lane;
    int i0 = eidx[2*t], i1 = eidx[2*t+1];
    int m = (i0 == e) + (i1 == e);
    int v = m;
    #pragma unroll
    for (int off = 1; off < 64; off <<= 1){
      int u = __shfl_up(v, off);
      if (lane >= off) v += u;
    }
    int pos = base + v;
    if (m > 0){
      bool dropped = pos > CAP;
      int slot = dropped ? -1 : (e * CAP + pos - 1);
      if (!dropped) assign[slot] = t;
      if (i0 == e) perm[2*t]   = slot;
      if (i1 == e) perm[2*t+1] = slot;
    }
    base += __shfl(v, 63);
  }
  if (lane == 0) counts[e] = base < CAP ? base : CAP;
}

// ---- device transpose tile: (R x Cc) fp32 -> (Cc x R) bf16, 128 rows x 64 cols ---
// pad 67: write-phase bank stride 8*67 ushorts -> 8 distinct banks (~2-way, free)
__device__ __forceinline__ void do_transpose(const float* __restrict__ src,
                                             unsigned short* __restrict__ dst,
                                             int R, int Cc, int c0, int r0,
                                             unsigned short* tile /*128*67*/){
  int tr = threadIdx.x >> 4, tc = threadIdx.x & 15;
  #pragma unroll
  for (int it = 0; it < 8; ++it){
    int r = it*16 + tr;
    float4 v = *(const float4*)(src + (size_t)(r0 + r) * Cc + c0 + tc*4);
    tile[r*67 + tc*4+0] = f2bf(v.x);
    tile[r*67 + tc*4+1] = f2bf(v.y);
    tile[r*67 + tc*4+2] = f2bf(v.z);
    tile[r*67 + tc*4+3] = f2bf(v.w);
  }
  __syncthreads();
  int j0 = tc * 8;
  #pragma unroll
  for (int it = 0; it < 4; ++it){
    int i = it*16 + tr;
    bf16x8 o;
    #pragma unroll
    for (int r = 0; r < 8; ++r) o[r] = (short)tile[(j0 + r)*67 + i];
    *(bf16x8*)(dst + (size_t)(c0 + i) * R + r0 + j0) = o;
  }
}

// ---- prep: wgu transpose (blocks 0..5631) + gather (blocks 5632..22015) --------
__global__ void prep_kernel(const float* __restrict__ wgu, unsigned short* __restrict__ wguT,
                            const float* __restrict__ hidden,
                            const int* __restrict__ assign, const int* __restrict__ counts,
                            unsigned short* __restrict__ x)
{
  __shared__ unsigned short tile[128*67];
  int b = blockIdx.x;
  if (b < 5632){
    int c0 = (b % 88) * 64;
    int r0 = ((b / 88) & 7) * 128;
    int e  = b / 704;
    do_transpose(wgu + (size_t)e * HID * (2*INTER), wguT + (size_t)e * HID * (2*INTER),
                 HID, 2*INTER, c0, r0, tile);
  } else {
    int s = b - 5632;
    int e = s / CAP, local = s % CAP;
    if (local >= ((counts[e] + 127) & ~127)) return;
    int tok = assign[s];
    int c = threadIdx.x * 4;
    float4 v = *(const float4*)(hidden + (size_t)tok * HID + c);
    ushort4 o; o.x = f2bf(v.x); o.y = f2bf(v.y); o.z = f2bf(v.z); o.w = f2bf(v.w);
    *(ushort4*)(x + (size_t)s * HID + c) = o;
  }
}

// ---------------- GEMM staging (swizzled, rule #21) ------------------------------
template<int ROWS>
__device__ __forceinline__ void stage_tile(const unsigned short* gbase, int ldk, int k0,
                                           unsigned short* lds, int lane, int wid){
  #pragma unroll
  for (int c = 0; c < ROWS/32; ++c){
    int rb = c*32 + wid*8;                 // wave-uniform LDS dest
    int row = rb + (lane >> 3);
    int slot = (lane & 7) ^ (row & 7);     // pre-swizzled global source
    const char* src = (const char*)(gbase + (size_t)row * ldk + k0) + slot*16;
    gload_lds16(src, (char*)lds + rb*128);
  }
}

__device__ __forceinline__ bf16x8 lds_frag(const unsigned short* lds, int row, int kslot){
  int slot = kslot ^ (row & 7);            // swizzled read
  return *(const bf16x8*)((const char*)lds + row*128 + slot*16);
}

// ---- GEMM1(+SiLU, BN=64 dual) body over carved smem -----------------------------
__device__ void gemm1_body(const unsigned short* __restrict__ A,
                           const unsigned short* __restrict__ Bt,
                           unsigned short* __restrict__ O,
                           const int* __restrict__ counts,
                           int nx, int my, int e, unsigned short* smem)
{
  int m0 = my * 128;
  if (m0 >= counts[e]) return;
  int n0 = nx * 64;
  unsigned short* Al = smem;               // 128*64
  unsigned short* Bg = smem + 8192;        // 64*64
  unsigned short* Bu = smem + 12288;       // 64*64

  int tid = threadIdx.x, lane = tid & 63, wid = tid >> 6;
  int wm = wid >> 1, wn = wid & 1;
  int lo = lane & 15, hi = lane >> 4;

  const unsigned short* Ab  = A  + ((size_t)e * CAP + m0) * HID;
  const unsigned short* Bgb = Bt + (size_t)e * (2*INTER) * HID + (size_t)n0 * HID;
  const unsigned short* Bub = Bt + (size_t)e * (2*INTER) * HID + (size_t)(INTER + n0) * HID;

  f32x4 accg[4][2] = {}, accu[4][2] = {};

  for (int k0 = 0; k0 < HID; k0 += 64){
    stage_tile<128>(Ab,  HID, k0, Al, lane, wid);
    stage_tile<64>(Bgb, HID, k0, Bg, lane, wid);
    stage_tile<64>(Bub, HID, k0, Bu, lane, wid);
    __syncthreads();
    #pragma unroll
    for (int kk = 0; kk < 64; kk += 32){
      int kslot = (kk >> 3) + hi;
      bf16x8 af[4], bg_[2], bu_[2];
      #pragma unroll
      for (int m = 0; m < 4; ++m) af[m] = lds_frag(Al, wm*64 + m*16 + lo, kslot);
      #pragma unroll
      for (int n = 0; n < 2; ++n){
        bg_[n] = lds_frag(Bg, wn*32 + n*16 + lo, kslot);
        bu_[n] = lds_frag(Bu, wn*32 + n*16 + lo, kslot);
      }
      #pragma unroll
      for (int m = 0; m < 4; ++m){
        #pragma unroll
        for (int n = 0; n < 2; ++n){
          accg[m][n] = __builtin_amdgcn_mfma_f32_16x16x32_bf16(af[m], bg_[n], accg[m][n], 0, 0, 0);
          accu[m][n] = __builtin_amdgcn_mfma_f32_16x16x32_bf16(af[m], bu_[n], accu[m][n], 0, 0, 0);
        }
      }
    }
    __syncthreads();
  }

  #pragma unroll
  for (int m = 0; m < 4; ++m){
    #pragma unroll
    for (int n = 0; n < 2; ++n){
      int gr = m0 + wm*64 + m*16 + hi*4;
      int gc = n0 + wn*32 + n*16 + lo;
      #pragma unroll
      for (int j = 0; j < 4; ++j){
        float g = accg[m][n][j], u = accu[m][n][j];
        float v = g / (1.f + __expf(-g)) * u;
        O[((size_t)e * CAP + gr + j) * INTER + gc] = f2bf(v);
      }
    }
  }
}

// ---- merged: GEMM1 and wdn-T interleaved 2:1 so transpose BW hides under MFMA ---
// b%3==2 -> transpose tile b/3 (2816); else GEMM tile (b/3)*2 + b%3 (5632).
__global__ __launch_bounds__(256, 4)
void gemm1_wdnT(const unsigned short* __restrict__ x, const unsigned short* __restrict__ wguT,
                unsigned short* __restrict__ h, const int* __restrict__ counts,
                const float* __restrict__ wdn, unsigned short* __restrict__ wdT)
{
  __shared__ unsigned short smem[16384];   // 32KB: GEMM carve or transpose tile
  int b = blockIdx.x;
  if ((b % 3) == 2){
    int t = b / 3;
    int c0 = (t % 16) * 64;                // Cc=HID: 16 col-tiles
    int r0 = ((t / 16) % 22) * 128;        // R=INTER: 22 row-tiles
    int e  = t / 352;
    do_transpose(wdn + (size_t)e * INTER * HID, wdT + (size_t)e * INTER * HID,
                 INTER, HID, c0, r0, smem);
  } else {
    int g = (b / 3) * 2 + (b % 3);
    int nx = g % 44, my = (g / 44) & 15, e = g / 704;
    gemm1_body(x, wguT, h, counts, nx, my, e, smem);
  }
}

// ---- GEMM2: BN=128, split-K=2 ---------------------------------------------------
__global__ __launch_bounds__(256, 4)
void gemm2(const unsigned short* __restrict__ A,    // (E*CAP) x INTER
           const unsigned short* __restrict__ Bt,   // per-expert (HID x INTER) B^T
           unsigned short* __restrict__ O,          // P0
           unsigned short* __restrict__ O2,         // P1
           const int* __restrict__ counts)
{
  int z = blockIdx.z;
  int e = z >> 1, kc = z & 1;
  int m0 = blockIdx.y * 128;
  if (m0 >= counts[e]) return;
  int n0 = blockIdx.x * 128;
  int kbase = kc * (INTER/2);
  unsigned short* Op = kc ? O2 : O;

  __shared__ unsigned short Al[128*64];
  __shared__ unsigned short Bg[128*64];

  int tid = threadIdx.x, lane = tid & 63, wid = tid >> 6;
  int wm = wid >> 1, wn = wid & 1;
  int lo = lane & 15, hi = lane >> 4;

  const unsigned short* Ab  = A  + ((size_t)e * CAP + m0) * INTER;
  const unsigned short* Bgb = Bt + (size_t)e * HID * INTER + (size_t)n0 * INTER;

  f32x4 accg[4][4] = {};

  for (int k0 = kbase; k0 < kbase + INTER/2; k0 += 64){
    stage_tile<128>(Ab,  INTER, k0, Al, lane, wid);
    stage_tile<128>(Bgb, INTER, k0, Bg, lane, wid);
    __syncthreads();
    #pragma unroll
    for (int kk = 0; kk < 64; kk += 32){
      int kslot = (kk >> 3) + hi;
      bf16x8 af[4], bg_[4];
      #pragma unroll
      for (int m = 0; m < 4; ++m) af[m] = lds_frag(Al, wm*64 + m*16 + lo, kslot);
      #pragma unroll
      for (int n = 0; n < 4; ++n) bg_[n] = lds_frag(Bg, wn*64 + n*16 + lo, kslot);
      #pragma unroll
      for (int m = 0; m < 4; ++m){
        #pragma unroll
        for (int n = 0; n < 4; ++n)
          accg[m][n] = __builtin_amdgcn_mfma_f32_16x16x32_bf16(af[m], bg_[n], accg[m][n], 0, 0, 0);
      }
    }
    __syncthreads();
  }

  #pragma unroll
  for (int m = 0; m < 4; ++m){
    #pragma unroll
    for (int n = 0; n < 4; ++n){
      int gr = m0 + wm*64 + m*16 + hi*4;
      int gc = n0 + wn*64 + n*16 + lo;
      #pragma unroll
      for (int j = 0; j < 4; ++j)
        Op[((size_t)e * CAP + gr + j) * HID + gc] = f2bf(accg[m][n][j]);
    }
  }
}

// ---------------- combine: out[t] = sum_k w_k * (P0+P1)[perm[t,k]] --------------
__global__ void combine_kernel(const unsigned short* __restrict__ p0,
                               const unsigned short* __restrict__ p1,
                               const int* __restrict__ perm,
                               const int* __restrict__ eidx,
                               const float* __restrict__ aff,
                               float* __restrict__ out)
{
  int t = blockIdx.x;
  int i0 = eidx[2*t], i1 = eidx[2*t+1];
  int q0 = perm[2*t], q1 = perm[2*t+1];
  float a0 = (q0 >= 0) ? aff[t*NEXP + i0] : 0.f;
  float a1 = (q1 >= 0) ? aff[t*NEXP + i1] : 0.f;
  float denom = (i0 == i1) ? fabsf(a0) : (fabsf(a0) + fabsf(a1));
  denom = fmaxf(denom, 1e-12f);
  float w0 = a0 / denom, w1 = a1 / denom;
  size_t s0 = (size_t)(q0 >= 0 ? q0 : 0) * HID;
  size_t s1 = (size_t)(q1 >= 0 ? q1 : 0) * HID;
  int c = threadIdx.x * 4;
  ushort4 v0a = *(const ushort4*)(p0 + s0 + c);
  ushort4 v0b = *(const ushort4*)(p1 + s0 + c);
  ushort4 v1a = *(const ushort4*)(p0 + s1 + c);
  ushort4 v1b = *(const ushort4*)(p1 + s1 + c);
  float4 o;
  o.x = w0*(bf2f(v0a.x)+bf2f(v0b.x)) + w1*(bf2f(v1a.x)+bf2f(v1b.x));
  o.y = w0*(bf2f(v0a.y)+bf2f(v0b.y)) + w1*(bf2f(v1a.y)+bf2f(v1b.y));
  o.z = w0*(bf2f(v0a.z)+bf2f(v0b.z)) + w1*(bf2f(v1a.z)+bf2f(v1b.z));
  o.w = w0*(bf2f(v0a.w)+bf2f(v0b.w)) + w1*(bf2f(v1a.w)+bf2f(v1b.w));
  *(float4*)(out + (size_t)t * HID + c) = o;
}

extern "C" void kernel_launch(void* const* d_in, const int* in_sizes, int n_in,
                              void* d_out, int out_size, void* d_ws, size_t ws_size,
                              hipStream_t stream)
{
  const float* hidden = (const float*)d_in[0];
  const float* aff    = (const float*)d_in[1];
  const int*   eidx   = (const int*)d_in[2];
  const float* wgu    = (const float*)d_in[3];
  const float* wdn    = (const float*)d_in[4];
  float* out = (float*)d_out;

  char* ws = (char*)d_ws;
  // ws layout (bytes), total ~298 MiB:
  //   wguT  @ 0           : 92,274,688
  //   wdT   @ 92,274,688  : 46,137,344
  //   h     @ 138,412,032 : 92,274,688
  //   x/P0  @ 230,686,720 : 33,554,432
  //   p1    @ 264,241,152 : 33,554,432
  //   assign @297,795,584 / perm @297,861,120 / counts @297,893,888
  unsigned short* wguT = (unsigned short*)(ws + 0);
  unsigned short* wdT  = (unsigned short*)(ws + 92274688);
  unsigned short* h    = (unsigned short*)(ws + 138412032);
  unsigned short* x    = (unsigned short*)(ws + 230686720);
  unsigned short* p1   = (unsigned short*)(ws + 264241152);
  int* assign          = (int*)(ws + 297795584);
  int* perm            = (int*)(ws + 297861120);
  int* counts          = (int*)(ws + 297893888);

  routing_kernel<<<1, 512, 0, stream>>>(eidx, assign, perm, counts);
  // wgu transpose (5632 blocks) + gather (16384 blocks), one launch
  prep_kernel<<<dim3(22016), 256, 0, stream>>>(wgu, wguT, hidden, assign, counts, x);
  // GEMM1 + wdn transpose, interleaved 2:1 (transpose BW hides under MFMA)
  gemm1_wdnT<<<dim3(8448), 256, 0, stream>>>(x, wguT, h, counts, wdn, wdT);
  // GEMM2 split-K=2: P0 + P1
  gemm2<<<dim3(8, 16, 16), 256, 0, stream>>>(h, wdT, x, p1, counts);
  combine_kernel<<<dim3(T_TOK), 256, 0, stream>>>(x, p1, perm, eidx, aff, out);
}

// Round 19
// 289.327 us; speedup vs baseline: 1.1207x; 1.1207x over previous
//
#include <hip/hip_runtime.h>

#define T_TOK 4096
#define NEXP  8
#define HID   1024
#define INTER 2816
#define CAP   2048

typedef __attribute__((ext_vector_type(8))) short bf16x8;
typedef __attribute__((ext_vector_type(4))) float f32x4;

__device__ __forceinline__ float bf2f(unsigned short u){
  union { unsigned int i; float f; } c; c.i = ((unsigned int)u) << 16; return c.f;
}
__device__ __forceinline__ unsigned short f2bf(float f){
  union { float f; unsigned int i; } c; c.f = f;
  unsigned int x = c.i;
  unsigned int r = (x + 0x7fffu + ((x >> 16) & 1u)) >> 16;
  return (unsigned short)r;
}

__device__ __forceinline__ void gload_lds16(const void* g, void* l){
  __builtin_amdgcn_global_load_lds(
      (const __attribute__((address_space(1))) void*)g,
      (__attribute__((address_space(3))) void*)l, 16, 0, 0);
}

// ---------------- routing: 1 block, 512 threads, wave w owns expert w ----------
__global__ void routing_kernel(const int* __restrict__ eidx,
                               int* __restrict__ assign,
                               int* __restrict__ perm,
                               int* __restrict__ counts)
{
  int tid = threadIdx.x;
  for (int i = tid; i < NEXP * CAP; i += 512) assign[i] = 0;
  __syncthreads();
  int e = tid >> 6;
  int lane = tid & 63;
  int base = 0;
  for (int t0 = 0; t0 < T_TOK; t0 += 64){
    int t = t0 + lane;
    int i0 = eidx[2*t], i1 = eidx[2*t+1];
    int m = (i0 == e) + (i1 == e);
    int v = m;
    #pragma unroll
    for (int off = 1; off < 64; off <<= 1){
      int u = __shfl_up(v, off);
      if (lane >= off) v += u;
    }
    int pos = base + v;
    if (m > 0){
      bool dropped = pos > CAP;
      int slot = dropped ? -1 : (e * CAP + pos - 1);
      if (!dropped) assign[slot] = t;
      if (i0 == e) perm[2*t]   = slot;
      if (i1 == e) perm[2*t+1] = slot;
    }
    base += __shfl(v, 63);
  }
  if (lane == 0) counts[e] = base < CAP ? base : CAP;
}

// ---- device transpose tile: (R x Cc) fp32 -> (Cc x R) bf16, 128 rows x 64 cols ---
// pad 67: write-phase bank stride 8*67 ushorts -> 8 distinct banks (~2-way, free)
// non-temporal loads (native ext_vector f32x4): single-use weight stream must not
// evict GEMM panels from L2.
__device__ __forceinline__ void do_transpose(const float* __restrict__ src,
                                             unsigned short* __restrict__ dst,
                                             int R, int Cc, int c0, int r0,
                                             unsigned short* tile /*128*67*/){
  int tr = threadIdx.x >> 4, tc = threadIdx.x & 15;
  #pragma unroll
  for (int it = 0; it < 8; ++it){
    int r = it*16 + tr;
    f32x4 v = __builtin_nontemporal_load(
        (const f32x4*)(src + (size_t)(r0 + r) * Cc + c0 + tc*4));
    tile[r*67 + tc*4+0] = f2bf(v[0]);
    tile[r*67 + tc*4+1] = f2bf(v[1]);
    tile[r*67 + tc*4+2] = f2bf(v[2]);
    tile[r*67 + tc*4+3] = f2bf(v[3]);
  }
  __syncthreads();
  int j0 = tc * 8;
  #pragma unroll
  for (int it = 0; it < 4; ++it){
    int i = it*16 + tr;
    bf16x8 o;
    #pragma unroll
    for (int r = 0; r < 8; ++r) o[r] = (short)tile[(j0 + r)*67 + i];
    *(bf16x8*)(dst + (size_t)(c0 + i) * R + r0 + j0) = o;
  }
}

// ---- prep: wgu transpose (blocks 0..5631) + gather (blocks 5632..22015) --------
__global__ void prep_kernel(const float* __restrict__ wgu, unsigned short* __restrict__ wguT,
                            const float* __restrict__ hidden,
                            const int* __restrict__ assign, const int* __restrict__ counts,
                            unsigned short* __restrict__ x)
{
  __shared__ unsigned short tile[128*67];
  int b = blockIdx.x;
  if (b < 5632){
    int c0 = (b % 88) * 64;
    int r0 = ((b / 88) & 7) * 128;
    int e  = b / 704;
    do_transpose(wgu + (size_t)e * HID * (2*INTER), wguT + (size_t)e * HID * (2*INTER),
                 HID, 2*INTER, c0, r0, tile);
  } else {
    int s = b - 5632;
    int e = s / CAP, local = s % CAP;
    if (local >= ((counts[e] + 127) & ~127)) return;
    int tok = assign[s];
    int c = threadIdx.x * 4;
    float4 v = *(const float4*)(hidden + (size_t)tok * HID + c);
    ushort4 o; o.x = f2bf(v.x); o.y = f2bf(v.y); o.z = f2bf(v.z); o.w = f2bf(v.w);
    *(ushort4*)(x + (size_t)s * HID + c) = o;
  }
}

// ---------------- GEMM staging (swizzled, rule #21) ------------------------------
template<int ROWS>
__device__ __forceinline__ void stage_tile(const unsigned short* gbase, int ldk, int k0,
                                           unsigned short* lds, int lane, int wid){
  #pragma unroll
  for (int c = 0; c < ROWS/32; ++c){
    int rb = c*32 + wid*8;                 // wave-uniform LDS dest
    int row = rb + (lane >> 3);
    int slot = (lane & 7) ^ (row & 7);     // pre-swizzled global source
    const char* src = (const char*)(gbase + (size_t)row * ldk + k0) + slot*16;
    gload_lds16(src, (char*)lds + rb*128);
  }
}

__device__ __forceinline__ bf16x8 lds_frag(const unsigned short* lds, int row, int kslot){
  int slot = kslot ^ (row & 7);            // swizzled read
  return *(const bf16x8*)((const char*)lds + row*128 + slot*16);
}

// ---- GEMM1(+SiLU, BN=64 dual) body over carved smem -----------------------------
__device__ void gemm1_body(const unsigned short* __restrict__ A,
                           const unsigned short* __restrict__ Bt,
                           unsigned short* __restrict__ O,
                           const int* __restrict__ counts,
                           int nx, int my, int e, unsigned short* smem)
{
  int m0 = my * 128;
  if (m0 >= counts[e]) return;
  int n0 = nx * 64;
  unsigned short* Al = smem;               // 128*64
  unsigned short* Bg = smem + 8192;        // 64*64
  unsigned short* Bu = smem + 12288;       // 64*64

  int tid = threadIdx.x, lane = tid & 63, wid = tid >> 6;
  int wm = wid >> 1, wn = wid & 1;
  int lo = lane & 15, hi = lane >> 4;

  const unsigned short* Ab  = A  + ((size_t)e * CAP + m0) * HID;
  const unsigned short* Bgb = Bt + (size_t)e * (2*INTER) * HID + (size_t)n0 * HID;
  const unsigned short* Bub = Bt + (size_t)e * (2*INTER) * HID + (size_t)(INTER + n0) * HID;

  f32x4 accg[4][2] = {}, accu[4][2] = {};

  for (int k0 = 0; k0 < HID; k0 += 64){
    stage_tile<128>(Ab,  HID, k0, Al, lane, wid);
    stage_tile<64>(Bgb, HID, k0, Bg, lane, wid);
    stage_tile<64>(Bub, HID, k0, Bu, lane, wid);
    __syncthreads();
    #pragma unroll
    for (int kk = 0; kk < 64; kk += 32){
      int kslot = (kk >> 3) + hi;
      bf16x8 af[4], bg_[2], bu_[2];
      #pragma unroll
      for (int m = 0; m < 4; ++m) af[m] = lds_frag(Al, wm*64 + m*16 + lo, kslot);
      #pragma unroll
      for (int n = 0; n < 2; ++n){
        bg_[n] = lds_frag(Bg, wn*32 + n*16 + lo, kslot);
        bu_[n] = lds_frag(Bu, wn*32 + n*16 + lo, kslot);
      }
      #pragma unroll
      for (int m = 0; m < 4; ++m){
        #pragma unroll
        for (int n = 0; n < 2; ++n){
          accg[m][n] = __builtin_amdgcn_mfma_f32_16x16x32_bf16(af[m], bg_[n], accg[m][n], 0, 0, 0);
          accu[m][n] = __builtin_amdgcn_mfma_f32_16x16x32_bf16(af[m], bu_[n], accu[m][n], 0, 0, 0);
        }
      }
    }
    __syncthreads();
  }

  #pragma unroll
  for (int m = 0; m < 4; ++m){
    #pragma unroll
    for (int n = 0; n < 2; ++n){
      int gr = m0 + wm*64 + m*16 + hi*4;
      int gc = n0 + wn*32 + n*16 + lo;
      #pragma unroll
      for (int j = 0; j < 4; ++j){
        float g = accg[m][n][j], u = accu[m][n][j];
        float v = g / (1.f + __expf(-g)) * u;
        O[((size_t)e * CAP + gr + j) * INTER + gc] = f2bf(v);
      }
    }
  }
}

// ---- merged: GEMM1 first (blocks 0..5631), wdn transpose backfills (5632..8447) -
__global__ __launch_bounds__(256, 4)
void gemm1_wdnT(const unsigned short* __restrict__ x, const unsigned short* __restrict__ wguT,
                unsigned short* __restrict__ h, const int* __restrict__ counts,
                const float* __restrict__ wdn, unsigned short* __restrict__ wdT)
{
  __shared__ unsigned short smem[16384];   // 32KB: GEMM carve or transpose tile
  int b = blockIdx.x;
  if (b < 5632){
    int nx = b % 44, my = (b / 44) & 15, e = b / 704;
    gemm1_body(x, wguT, h, counts, nx, my, e, smem);
  } else {
    int t = b - 5632;
    int c0 = (t % 16) * 64;                // Cc=HID: 16 col-tiles
    int r0 = ((t / 16) % 22) * 128;        // R=INTER: 22 row-tiles
    int e  = t / 352;
    do_transpose(wdn + (size_t)e * INTER * HID, wdT + (size_t)e * INTER * HID,
                 INTER, HID, c0, r0, smem);
  }
}

// ---- GEMM2: BN=128, split-K=2 ---------------------------------------------------
__global__ __launch_bounds__(256, 4)
void gemm2(const unsigned short* __restrict__ A,    // (E*CAP) x INTER
           const unsigned short* __restrict__ Bt,   // per-expert (HID x INTER) B^T
           unsigned short* __restrict__ O,          // P0
           unsigned short* __restrict__ O2,         // P1
           const int* __restrict__ counts)
{
  int z = blockIdx.z;
  int e = z >> 1, kc = z & 1;
  int m0 = blockIdx.y * 128;
  if (m0 >= counts[e]) return;
  int n0 = blockIdx.x * 128;
  int kbase = kc * (INTER/2);
  unsigned short* Op = kc ? O2 : O;

  __shared__ unsigned short Al[128*64];
  __shared__ unsigned short Bg[128*64];

  int tid = threadIdx.x, lane = tid & 63, wid = tid >> 6;
  int wm = wid >> 1, wn = wid & 1;
  int lo = lane & 15, hi = lane >> 4;

  const unsigned short* Ab  = A  + ((size_t)e * CAP + m0) * INTER;
  const unsigned short* Bgb = Bt + (size_t)e * HID * INTER + (size_t)n0 * INTER;

  f32x4 accg[4][4] = {};

  for (int k0 = kbase; k0 < kbase + INTER/2; k0 += 64){
    stage_tile<128>(Ab,  INTER, k0, Al, lane, wid);
    stage_tile<128>(Bgb, INTER, k0, Bg, lane, wid);
    __syncthreads();
    #pragma unroll
    for (int kk = 0; kk < 64; kk += 32){
      int kslot = (kk >> 3) + hi;
      bf16x8 af[4], bg_[4];
      #pragma unroll
      for (int m = 0; m < 4; ++m) af[m] = lds_frag(Al, wm*64 + m*16 + lo, kslot);
      #pragma unroll
      for (int n = 0; n < 4; ++n) bg_[n] = lds_frag(Bg, wn*64 + n*16 + lo, kslot);
      #pragma unroll
      for (int m = 0; m < 4; ++m){
        #pragma unroll
        for (int n = 0; n < 4; ++n)
          accg[m][n] = __builtin_amdgcn_mfma_f32_16x16x32_bf16(af[m], bg_[n], accg[m][n], 0, 0, 0);
      }
    }
    __syncthreads();
  }

  #pragma unroll
  for (int m = 0; m < 4; ++m){
    #pragma unroll
    for (int n = 0; n < 4; ++n){
      int gr = m0 + wm*64 + m*16 + hi*4;
      int gc = n0 + wn*64 + n*16 + lo;
      #pragma unroll
      for (int j = 0; j < 4; ++j)
        Op[((size_t)e * CAP + gr + j) * HID + gc] = f2bf(accg[m][n][j]);
    }
  }
}

// ---------------- combine: out[t] = sum_k w_k * (P0+P1)[perm[t,k]] --------------
__global__ void combine_kernel(const unsigned short* __restrict__ p0,
                               const unsigned short* __restrict__ p1,
                               const int* __restrict__ perm,
                               const int* __restrict__ eidx,
                               const float* __restrict__ aff,
                               float* __restrict__ out)
{
  int t = blockIdx.x;
  int i0 = eidx[2*t], i1 = eidx[2*t+1];
  int q0 = perm[2*t], q1 = perm[2*t+1];
  float a0 = (q0 >= 0) ? aff[t*NEXP + i0] : 0.f;
  float a1 = (q1 >= 0) ? aff[t*NEXP + i1] : 0.f;
  float denom = (i0 == i1) ? fabsf(a0) : (fabsf(a0) + fabsf(a1));
  denom = fmaxf(denom, 1e-12f);
  float w0 = a0 / denom, w1 = a1 / denom;
  size_t s0 = (size_t)(q0 >= 0 ? q0 : 0) * HID;
  size_t s1 = (size_t)(q1 >= 0 ? q1 : 0) * HID;
  int c = threadIdx.x * 4;
  ushort4 v0a = *(const ushort4*)(p0 + s0 + c);
  ushort4 v0b = *(const ushort4*)(p1 + s0 + c);
  ushort4 v1a = *(const ushort4*)(p0 + s1 + c);
  ushort4 v1b = *(const ushort4*)(p1 + s1 + c);
  float4 o;
  o.x = w0*(bf2f(v0a.x)+bf2f(v0b.x)) + w1*(bf2f(v1a.x)+bf2f(v1b.x));
  o.y = w0*(bf2f(v0a.y)+bf2f(v0b.y)) + w1*(bf2f(v1a.y)+bf2f(v1b.y));
  o.z = w0*(bf2f(v0a.z)+bf2f(v0b.z)) + w1*(bf2f(v1a.z)+bf2f(v1b.z));
  o.w = w0*(bf2f(v0a.w)+bf2f(v0b.w)) + w1*(bf2f(v1a.w)+bf2f(v1b.w));
  *(float4*)(out + (size_t)t * HID + c) = o;
}

extern "C" void kernel_launch(void* const* d_in, const int* in_sizes, int n_in,
                              void* d_out, int out_size, void* d_ws, size_t ws_size,
                              hipStream_t stream)
{
  const float* hidden = (const float*)d_in[0];
  const float* aff    = (const float*)d_in[1];
  const int*   eidx   = (const int*)d_in[2];
  const float* wgu    = (const float*)d_in[3];
  const float* wdn    = (const float*)d_in[4];
  float* out = (float*)d_out;

  char* ws = (char*)d_ws;
  // ws layout (bytes), total ~298 MiB:
  //   wguT  @ 0           : 92,274,688
  //   wdT   @ 92,274,688  : 46,137,344
  //   h     @ 138,412,032 : 92,274,688
  //   x/P0  @ 230,686,720 : 33,554,432
  //   p1    @ 264,241,152 : 33,554,432
  //   assign @297,795,584 / perm @297,861,120 / counts @297,893,888
  unsigned short* wguT = (unsigned short*)(ws + 0);
  unsigned short* wdT  = (unsigned short*)(ws + 92274688);
  unsigned short* h    = (unsigned short*)(ws + 138412032);
  unsigned short* x    = (unsigned short*)(ws + 230686720);
  unsigned short* p1   = (unsigned short*)(ws + 264241152);
  int* assign          = (int*)(ws + 297795584);
  int* perm            = (int*)(ws + 297861120);
  int* counts          = (int*)(ws + 297893888);

  routing_kernel<<<1, 512, 0, stream>>>(eidx, assign, perm, counts);
  // wgu transpose (5632 blocks) + gather (16384 blocks), one launch
  prep_kernel<<<dim3(22016), 256, 0, stream>>>(wgu, wguT, hidden, assign, counts, x);
  // GEMM1 (5632 blocks, dispatched first) + wdn transpose (2816 blocks backfill)
  gemm1_wdnT<<<dim3(8448), 256, 0, stream>>>(x, wguT, h, counts, wdn, wdT);
  // GEMM2 split-K=2: P0 + P1
  gemm2<<<dim3(8, 16, 16), 256, 0, stream>>>(h, wdT, x, p1, counts);
  combine_kernel<<<dim3(T_TOK), 256, 0, stream>>>(x, p1, perm, eidx, aff, out);
}